// Round 9
// baseline (2182.626 us; speedup 1.0000x reference)
//
#include <hip/hip_runtime.h>
#include <hip/hip_cooperative_groups.h>
#include <cmath>

namespace cg = cooperative_groups;

// ConvLSTM2D forward, R9: persistent cooperative kernel (R8 + halo-base fix).
// R8 bug: pos0 baked the interior (+1,+1) offset into the K-loop window base,
// shifting the conv window and reading past hpatch (pos 390 > 364) -> NaN.
// Correct frames: K-loop window base = (py,px) in halo coords (top-left of the
// 3x3 window, halo origin = (-1,-1)); epilogue interior write = (py+1,px+1).
// Grid = 4x8x8 = 256 blocks of 512 threads = exactly 1 block/CU -> cooperative
// capacity guaranteed. Block: 24x12 tile x N=256, 8 waves; wave = (slice=w&3,
// mhalf=w>>2), M=144 x N=64, 36 MFMA/K-step, in-register gate fusion.
// c block-pinned (XCD-L2-resident); interior h in LDS across steps; only the
// 76-position ring re-read from global per step.

#define HTOT 96
#define WTOT 96
#define CINX 8
#define FF   64
#define G4   256
#define BB   8
#define TT   16
#define TW   24
#define THH  12
#define HW_  26                    // halo width
#define HH_  14                    // halo height
#define NHP  (HW_*HH_)             // 364 halo positions
#define MT   9                     // m-tiles of 16 per wave (144 = 9*16)
#define HP   72                    // ushorts per halo position (64 + 8 pad; 36 dw == 4 mod 32)
#define NPOS (BB*HTOT*WTOT)        // 73728

typedef __attribute__((ext_vector_type(8))) short short8;   // 8 bf16 = 4 VGPRs
typedef __attribute__((ext_vector_type(4))) float floatx4;

union U16 { uint4 u; short8 s; };

__device__ __forceinline__ float hsig(float z) {
    return fminf(fmaxf(0.2f * z + 0.5f, 0.f), 1.f);
}

__device__ __forceinline__ float ftanh(float x) {
    float e = __expf(-2.f * fabsf(x));
    float t = (1.f - e) / (1.f + e);
    return copysignf(t, x);
}

__device__ __forceinline__ ushort f2bf(float f) {            // RNE fp32->bf16
    unsigned u = __float_as_uint(f);
    u = (u + 0x7fff + ((u >> 16) & 1)) >> 16;
    return (ushort)u;
}

// ---- prep: x fp32 -> bf16 ----
__global__ __launch_bounds__(256) void conv_x_bf16(const float* __restrict__ x,
                                                   ushort* __restrict__ xbf, int n4) {
    int i = blockIdx.x * 256 + threadIdx.x;
    if (i >= n4) return;
    float4 v = ((const float4*)x)[i];
    ushort4 o;
    o.x = f2bf(v.x); o.y = f2bf(v.y); o.z = f2bf(v.z); o.w = f2bf(v.w);
    ((ushort4*)xbf)[i] = o;
}

// ---- prep: weights -> per-slice slab stream Bp[(slice*21+s)*256 + g*64 + lane] (16B units)
__global__ __launch_bounds__(256) void prep_w(const float* __restrict__ Wx,
                                              const float* __restrict__ Wh,
                                              ushort* __restrict__ Bp) {
    int idx = blockIdx.x * 256 + threadIdx.x;
    if (idx >= 4 * 21 * 256) return;
    int lane = idx & 63;
    int g = (idx >> 6) & 3;
    int rest = idx >> 8;                             // slice*21 + s
    int s = rest % 21, slice = rest / 21;
    int q = lane >> 4, col = lane & 15;
    int n = g * 64 + slice * 16 + col;
    ushort o[8];
    if (s < 18) {
        int tap = s >> 1;
        int cbase = (s & 1) * 32 + q * 8;
        #pragma unroll
        for (int j = 0; j < 8; ++j)
            o[j] = f2bf(Wh[((size_t)tap * FF + cbase + j) * G4 + n]);
    } else {
        int tap = (s - 18) * 4 + q;                  // packed x-taps; >8 -> zero pad
        #pragma unroll
        for (int j = 0; j < 8; ++j)
            o[j] = (tap < 9) ? f2bf(Wx[((size_t)tap * CINX + j) * G4 + n]) : (ushort)0;
    }
    U16 u;
    #pragma unroll
    for (int j = 0; j < 8; ++j) ((ushort*)&u)[j] = o[j];
    ((uint4*)Bp)[idx] = u.u;
}

// ---- persistent kernel: all 16 timesteps, grid.sync between steps ----
__global__ __launch_bounds__(512, 2) void convlstm_persist(
    const ushort* __restrict__ xbf,
    ushort* __restrict__ hG0,            // h ping [slice][pos][16] bf16
    ushort* __restrict__ hG1,            // h pong
    float* __restrict__ cS,              // c state [slice][pos][16] fp32 (L2-pinned)
    const ushort* __restrict__ Bp,
    const float* __restrict__ bias,
    float* __restrict__ out)
{
    __shared__ ushort hpatch[NHP * HP];  // 26x14 halo x 64 h-ch (+pad)  52.4 KB
    __shared__ ushort xpatch[NHP * 8];   // 26x14 halo x 8 x-ch           5.8 KB

    cg::grid_group grid = cg::this_grid();

    const int tid = threadIdx.x;
    const int x0 = blockIdx.x * TW, y0 = blockIdx.y * THH, bb = blockIdx.z;
    const int w = tid >> 6, lane = tid & 63, q = lane >> 4, col = lane & 15;
    const int slice = w & 3, mh = w >> 2;

    // zero hpatch once (h_{-1} = 0)
    for (int i = tid; i < NHP * HP / 8; i += 512)
        ((uint4*)hpatch)[i] = make_uint4(0, 0, 0, 0);

    const uint4* Bp4 = (const uint4*)Bp + (size_t)slice * 21 * 256;

    float bv[4];
    #pragma unroll
    for (int g = 0; g < 4; ++g) bv[g] = bias[g * 64 + slice * 16 + col];

    // K-loop window base: top-left of the 3x3 window in halo coords.
    // Output tile pos (py,px) -> halo (py+1,px+1); window base = (py,px).
    int pos0[MT];
    #pragma unroll
    for (int mt = 0; mt < MT; ++mt) {
        int p = mh * 144 + mt * 16 + col;            // 0..287 tile position
        pos0[mt] = (p / TW) * HW_ + (p % TW);
    }
    int xoff[3];
    #pragma unroll
    for (int j = 0; j < 3; ++j) {
        int tap = j * 4 + q; if (tap > 8) tap = 8;   // padded taps: B rows are zero
        xoff[j] = ((tap / 3) * HW_ + (tap % 3)) * 8;
    }

    #pragma unroll 1
    for (int t = 0; t < TT; ++t) {
        ushort* hw       = (t & 1) ? hG1 : hG0;      // h_t written here
        const ushort* hr = (t & 1) ? hG0 : hG1;      // h_{t-1} ring read from here

        // ---- stage halo ring of h (76 positions); interior already in LDS ----
        if (t > 0) {
            for (int e = tid; e < 76 * 8; e += 512) {
                int r = e >> 3, part = e & 7;
                int hy, hx;
                if (r < 26)      { hy = 0;       hx = r; }
                else if (r < 52) { hy = HH_ - 1; hx = r - 26; }
                else             { int r2 = r - 52; hy = 1 + (r2 >> 1); hx = (r2 & 1) * (HW_ - 1); }
                int gy = y0 - 1 + hy, gx = x0 - 1 + hx;
                uint4 v = make_uint4(0, 0, 0, 0);
                if (gy >= 0 && gy < HTOT && gx >= 0 && gx < WTOT) {
                    size_t gpos = ((size_t)bb * HTOT + gy) * WTOT + gx;
                    v = *(const uint4*)(hr + ((size_t)(part >> 1) * NPOS + gpos) * 16 + (part & 1) * 8);
                }
                *(uint4*)(hpatch + (hy * HW_ + hx) * HP + part * 8) = v;
            }
        }
        // ---- stage x halo for this t ----
        if (tid < NHP) {
            int hy = tid / HW_, hx = tid - hy * HW_;
            int gy = y0 - 1 + hy, gx = x0 - 1 + hx;
            uint4 v = make_uint4(0, 0, 0, 0);
            if (gy >= 0 && gy < HTOT && gx >= 0 && gx < WTOT)
                v = *(const uint4*)(xbf + ((((size_t)bb * TT + t) * HTOT + gy) * WTOT + gx) * CINX);
            *(uint4*)(xpatch + tid * 8) = v;
        }
        __syncthreads();

        floatx4 acc[MT][4];
        #pragma unroll
        for (int mt = 0; mt < MT; ++mt)
            #pragma unroll
            for (int g = 0; g < 4; ++g)
                acc[mt][g] = (floatx4){bv[g], bv[g], bv[g], bv[g]};

        // ---- K-loop: 21 steps of K=32, fully unrolled, barrier-free ----
        U16 b4[4], b4n[4];
        #pragma unroll
        for (int g = 0; g < 4; ++g)
            b4[g].u = Bp4[g * 64 + lane];

        #pragma unroll
        for (int s = 0; s < 21; ++s) {
            if (s < 20) {
                #pragma unroll
                for (int g = 0; g < 4; ++g)
                    b4n[g].u = Bp4[(s + 1) * 256 + g * 64 + lane];
            }
            if (s < 18) {
                const int tap = s >> 1, kh = s & 1;
                const int dy = tap / 3, dx = tap - 3 * dy;
                #pragma unroll
                for (int mt = 0; mt < MT; ++mt) {
                    U16 a;
                    a.u = *(const uint4*)(hpatch + (pos0[mt] + dy * HW_ + dx) * HP + kh * 32 + q * 8);
                    #pragma unroll
                    for (int g = 0; g < 4; ++g)
                        acc[mt][g] = __builtin_amdgcn_mfma_f32_16x16x32_bf16(a.s, b4[g].s, acc[mt][g], 0, 0, 0);
                }
            } else {
                #pragma unroll
                for (int mt = 0; mt < MT; ++mt) {
                    U16 a;
                    a.u = *(const uint4*)(xpatch + pos0[mt] * 8 + xoff[s - 18]);
                    #pragma unroll
                    for (int g = 0; g < 4; ++g)
                        acc[mt][g] = __builtin_amdgcn_mfma_f32_16x16x32_bf16(a.s, b4[g].s, acc[mt][g], 0, 0, 0);
                }
            }
            if (s < 20) {
                #pragma unroll
                for (int g = 0; g < 4; ++g) b4[g] = b4n[g];
            }
        }

        __syncthreads();   // all waves done reading hpatch before epilogue rewrites it

        // ---- epilogue: fused gates; c L2-hot; h -> LDS interior + global ring copy ----
        #pragma unroll
        for (int mt = 0; mt < MT; ++mt) {
            #pragma unroll
            for (int r = 0; r < 4; ++r) {
                int p = mh * 144 + mt * 16 + q * 4 + r;   // 0..287
                int py = p / TW, px = p - py * TW;
                size_t gpos = ((size_t)bb * HTOT + y0 + py) * WTOT + x0 + px;
                size_t idx = ((size_t)slice * NPOS + gpos) * 16 + col;
                float zi = acc[mt][0][r], zf = acc[mt][1][r];
                float zg = acc[mt][2][r], zo = acc[mt][3][r];
                float cn = hsig(zf) * cS[idx] + hsig(zi) * ftanh(zg);
                cS[idx] = cn;
                float hn = hsig(zo) * ftanh(cn);
                ushort hb = f2bf(hn);
                hpatch[((py + 1) * HW_ + px + 1) * HP + slice * 16 + col] = hb;  // interior for t+1
                hw[idx] = hb;                                                    // ring for neighbors
                if (t == TT - 1) out[gpos * 64 + slice * 16 + col] = hn;
            }
        }

        if (t < TT - 1) grid.sync();
    }
}

extern "C" void kernel_launch(void* const* d_in, const int* in_sizes, int n_in,
                              void* d_out, int out_size, void* d_ws, size_t ws_size,
                              hipStream_t stream) {
    const float* x  = (const float*)d_in[0];
    const float* Wx = (const float*)d_in[1];
    const float* Wh = (const float*)d_in[2];
    const float* b  = (const float*)d_in[3];

    const size_t NX = (size_t)BB * TT * HTOT * WTOT * CINX;  // 9,437,184
    const size_t NH = (size_t)NPOS * FF;                     // 4,718,592

    char* ws = (char*)d_ws;
    ushort* xbf = (ushort*)ws;                  ws += NX * 2;            // 18.9 MB
    ushort* hG0 = (ushort*)ws;                  ws += NH * 2;            //  9.4 MB
    ushort* hG1 = (ushort*)ws;                  ws += NH * 2;            //  9.4 MB
    float*  cs  = (float*)ws;                   ws += NH * 4;            // 18.9 MB
    ushort* Bp  = (ushort*)ws;                                           // 336 KB

    hipMemsetAsync(cs, 0, NH * 4, stream);

    conv_x_bf16<<<(int)((NX / 4 + 255) / 256), 256, 0, stream>>>(x, xbf, (int)(NX / 4));
    prep_w<<<(4 * 21 * 256 + 255) / 256, 256, 0, stream>>>(Wx, Wh, Bp);

    float* outp = (float*)d_out;
    void* args[] = { (void*)&xbf, (void*)&hG0, (void*)&hG1, (void*)&cs,
                     (void*)&Bp,  (void*)&b,   (void*)&outp };
    hipLaunchCooperativeKernel((const void*)convlstm_persist,
                               dim3(WTOT / TW, HTOT / THH, BB), dim3(512),
                               args, 0, stream);
}

// Round 10
// 1377.546 us; speedup vs baseline: 1.5844x; 1.5844x over previous
//
#include <hip/hip_runtime.h>
#include <hip/hip_cooperative_groups.h>
#include <cmath>

namespace cg = cooperative_groups;

// ConvLSTM2D forward, R10: persistent cooperative kernel, spill-free K-loop.
// R9 failure: full 21-step unroll + explicit double-buffers -> 128 VGPR + 144
// AGPR = 272 > 256 cap (512 thr x 1 block/CU) -> scratch spill -> 2.5 GB HBM
// fetch/dispatch. R10: rolled K-loop (#pragma unroll 1) + dist-1 B prefetch
// keeps regs ~220 <= 256. Everything else as R9: 256 blocks of 512 threads
// (exactly 1/CU, cooperative capacity guaranteed), block = 24x12 tile x N=256,
// wave = (slice, mhalf) M=144 x N=64, in-register gate fusion, c L2-pinned,
// interior h carried in LDS, 76-pos ring via global.

#define HTOT 96
#define WTOT 96
#define CINX 8
#define FF   64
#define G4   256
#define BB   8
#define TT   16
#define TW   24
#define THH  12
#define HW_  26                    // halo width
#define HH_  14                    // halo height
#define NHP  (HW_*HH_)             // 364 halo positions
#define MT   9                     // m-tiles of 16 per wave (144 = 9*16)
#define HP   72                    // ushorts per halo position (64 + 8 pad; 36 dw == 4 mod 32)
#define NPOS (BB*HTOT*WTOT)        // 73728

typedef __attribute__((ext_vector_type(8))) short short8;   // 8 bf16 = 4 VGPRs
typedef __attribute__((ext_vector_type(4))) float floatx4;

union U16 { uint4 u; short8 s; };

__device__ __forceinline__ float hsig(float z) {
    return fminf(fmaxf(0.2f * z + 0.5f, 0.f), 1.f);
}

__device__ __forceinline__ float ftanh(float x) {
    float e = __expf(-2.f * fabsf(x));
    float t = (1.f - e) / (1.f + e);
    return copysignf(t, x);
}

__device__ __forceinline__ ushort f2bf(float f) {            // RNE fp32->bf16
    unsigned u = __float_as_uint(f);
    u = (u + 0x7fff + ((u >> 16) & 1)) >> 16;
    return (ushort)u;
}

// ---- prep: x fp32 -> bf16 ----
__global__ __launch_bounds__(256) void conv_x_bf16(const float* __restrict__ x,
                                                   ushort* __restrict__ xbf, int n4) {
    int i = blockIdx.x * 256 + threadIdx.x;
    if (i >= n4) return;
    float4 v = ((const float4*)x)[i];
    ushort4 o;
    o.x = f2bf(v.x); o.y = f2bf(v.y); o.z = f2bf(v.z); o.w = f2bf(v.w);
    ((ushort4*)xbf)[i] = o;
}

// ---- prep: weights -> per-slice slab stream Bp[(slice*21+s)*256 + g*64 + lane] (16B units)
__global__ __launch_bounds__(256) void prep_w(const float* __restrict__ Wx,
                                              const float* __restrict__ Wh,
                                              ushort* __restrict__ Bp) {
    int idx = blockIdx.x * 256 + threadIdx.x;
    if (idx >= 4 * 21 * 256) return;
    int lane = idx & 63;
    int g = (idx >> 6) & 3;
    int rest = idx >> 8;                             // slice*21 + s
    int s = rest % 21, slice = rest / 21;
    int q = lane >> 4, col = lane & 15;
    int n = g * 64 + slice * 16 + col;
    ushort o[8];
    if (s < 18) {
        int tap = s >> 1;
        int cbase = (s & 1) * 32 + q * 8;
        #pragma unroll
        for (int j = 0; j < 8; ++j)
            o[j] = f2bf(Wh[((size_t)tap * FF + cbase + j) * G4 + n]);
    } else {
        int tap = (s - 18) * 4 + q;                  // packed x-taps; >8 -> zero pad
        #pragma unroll
        for (int j = 0; j < 8; ++j)
            o[j] = (tap < 9) ? f2bf(Wx[((size_t)tap * CINX + j) * G4 + n]) : (ushort)0;
    }
    U16 u;
    #pragma unroll
    for (int j = 0; j < 8; ++j) ((ushort*)&u)[j] = o[j];
    ((uint4*)Bp)[idx] = u.u;
}

// ---- persistent kernel: all 16 timesteps, grid.sync between steps ----
__global__ __launch_bounds__(512, 2) void convlstm_persist(
    const ushort* __restrict__ xbf,
    ushort* __restrict__ hG0,            // h ping [slice][pos][16] bf16
    ushort* __restrict__ hG1,            // h pong
    float* __restrict__ cS,              // c state [slice][pos][16] fp32 (L2-pinned)
    const ushort* __restrict__ Bp,
    const float* __restrict__ bias,
    float* __restrict__ out)
{
    __shared__ ushort hpatch[NHP * HP];  // 26x14 halo x 64 h-ch (+pad)  52.4 KB
    __shared__ ushort xpatch[NHP * 8];   // 26x14 halo x 8 x-ch           5.8 KB

    cg::grid_group grid = cg::this_grid();

    const int tid = threadIdx.x;
    const int x0 = blockIdx.x * TW, y0 = blockIdx.y * THH, bb = blockIdx.z;
    const int w = tid >> 6, lane = tid & 63, q = lane >> 4, col = lane & 15;
    const int slice = w & 3, mh = w >> 2;

    // zero hpatch once (h_{-1} = 0)
    for (int i = tid; i < NHP * HP / 8; i += 512)
        ((uint4*)hpatch)[i] = make_uint4(0, 0, 0, 0);

    const uint4* Bp4 = (const uint4*)Bp + (size_t)slice * 21 * 256;

    float bv[4];
    #pragma unroll
    for (int g = 0; g < 4; ++g) bv[g] = bias[g * 64 + slice * 16 + col];

    // K-loop window base: top-left of the 3x3 window in halo coords.
    int pos0[MT];
    #pragma unroll
    for (int mt = 0; mt < MT; ++mt) {
        int p = mh * 144 + mt * 16 + col;            // 0..287 tile position
        pos0[mt] = (p / TW) * HW_ + (p % TW);
    }
    int xoff[3];
    #pragma unroll
    for (int j = 0; j < 3; ++j) {
        int tap = j * 4 + q; if (tap > 8) tap = 8;   // padded taps: B rows are zero
        xoff[j] = ((tap / 3) * HW_ + (tap % 3)) * 8;
    }

    #pragma unroll 1
    for (int t = 0; t < TT; ++t) {
        ushort* hw       = (t & 1) ? hG1 : hG0;      // h_t written here
        const ushort* hr = (t & 1) ? hG0 : hG1;      // h_{t-1} ring read from here

        // ---- stage halo ring of h (76 positions); interior already in LDS ----
        if (t > 0) {
            for (int e = tid; e < 76 * 8; e += 512) {
                int r = e >> 3, part = e & 7;
                int hy, hx;
                if (r < 26)      { hy = 0;       hx = r; }
                else if (r < 52) { hy = HH_ - 1; hx = r - 26; }
                else             { int r2 = r - 52; hy = 1 + (r2 >> 1); hx = (r2 & 1) * (HW_ - 1); }
                int gy = y0 - 1 + hy, gx = x0 - 1 + hx;
                uint4 v = make_uint4(0, 0, 0, 0);
                if (gy >= 0 && gy < HTOT && gx >= 0 && gx < WTOT) {
                    size_t gpos = ((size_t)bb * HTOT + gy) * WTOT + gx;
                    v = *(const uint4*)(hr + ((size_t)(part >> 1) * NPOS + gpos) * 16 + (part & 1) * 8);
                }
                *(uint4*)(hpatch + (hy * HW_ + hx) * HP + part * 8) = v;
            }
        }
        // ---- stage x halo for this t ----
        if (tid < NHP) {
            int hy = tid / HW_, hx = tid - hy * HW_;
            int gy = y0 - 1 + hy, gx = x0 - 1 + hx;
            uint4 v = make_uint4(0, 0, 0, 0);
            if (gy >= 0 && gy < HTOT && gx >= 0 && gx < WTOT)
                v = *(const uint4*)(xbf + ((((size_t)bb * TT + t) * HTOT + gy) * WTOT + gx) * CINX);
            *(uint4*)(xpatch + tid * 8) = v;
        }
        __syncthreads();

        floatx4 acc[MT][4];
        #pragma unroll
        for (int mt = 0; mt < MT; ++mt)
            #pragma unroll
            for (int g = 0; g < 4; ++g)
                acc[mt][g] = (floatx4){bv[g], bv[g], bv[g], bv[g]};

        // ---- K-loop: 21 steps of K=32, ROLLED (reg pressure), dist-1 B prefetch ----
        U16 b4[4], b4n[4];
        #pragma unroll
        for (int g = 0; g < 4; ++g)
            b4[g].u = Bp4[g * 64 + lane];

        #pragma unroll 1
        for (int s = 0; s < 21; ++s) {
            if (s < 20) {
                #pragma unroll
                for (int g = 0; g < 4; ++g)
                    b4n[g].u = Bp4[(s + 1) * 256 + g * 64 + lane];
            }
            int abase;
            if (s < 18) {
                int tap = s >> 1;
                int dy = tap / 3, dx = tap - 3 * dy;          // scalar (s uniform)
                abase = (dy * HW_ + dx) * HP + (s & 1) * 32 + q * 8;
            } else {
                abase = xoff[s - 18];
            }
            #pragma unroll
            for (int mt = 0; mt < MT; ++mt) {
                U16 a;
                if (s < 18)
                    a.u = *(const uint4*)(hpatch + pos0[mt] * HP + abase);
                else
                    a.u = *(const uint4*)(xpatch + pos0[mt] * 8 + abase);
                #pragma unroll
                for (int g = 0; g < 4; ++g)
                    acc[mt][g] = __builtin_amdgcn_mfma_f32_16x16x32_bf16(a.s, b4[g].s, acc[mt][g], 0, 0, 0);
            }
            #pragma unroll
            for (int g = 0; g < 4; ++g) b4[g] = b4n[g];
        }

        __syncthreads();   // all waves done reading hpatch before epilogue rewrites it

        // ---- epilogue: fused gates; c L2-hot; h -> LDS interior + global ring copy ----
        #pragma unroll
        for (int mt = 0; mt < MT; ++mt) {
            #pragma unroll
            for (int r = 0; r < 4; ++r) {
                int p = mh * 144 + mt * 16 + q * 4 + r;   // 0..287
                int py = p / TW, px = p - py * TW;
                size_t gpos = ((size_t)bb * HTOT + y0 + py) * WTOT + x0 + px;
                size_t idx = ((size_t)slice * NPOS + gpos) * 16 + col;
                float zi = acc[mt][0][r], zf = acc[mt][1][r];
                float zg = acc[mt][2][r], zo = acc[mt][3][r];
                float cn = hsig(zf) * cS[idx] + hsig(zi) * ftanh(zg);
                cS[idx] = cn;
                float hn = hsig(zo) * ftanh(cn);
                ushort hb = f2bf(hn);
                hpatch[((py + 1) * HW_ + px + 1) * HP + slice * 16 + col] = hb;  // interior for t+1
                hw[idx] = hb;                                                    // ring for neighbors
                if (t == TT - 1) out[gpos * 64 + slice * 16 + col] = hn;
            }
        }

        if (t < TT - 1) grid.sync();
    }
}

extern "C" void kernel_launch(void* const* d_in, const int* in_sizes, int n_in,
                              void* d_out, int out_size, void* d_ws, size_t ws_size,
                              hipStream_t stream) {
    const float* x  = (const float*)d_in[0];
    const float* Wx = (const float*)d_in[1];
    const float* Wh = (const float*)d_in[2];
    const float* b  = (const float*)d_in[3];

    const size_t NX = (size_t)BB * TT * HTOT * WTOT * CINX;  // 9,437,184
    const size_t NH = (size_t)NPOS * FF;                     // 4,718,592

    char* ws = (char*)d_ws;
    ushort* xbf = (ushort*)ws;                  ws += NX * 2;            // 18.9 MB
    ushort* hG0 = (ushort*)ws;                  ws += NH * 2;            //  9.4 MB
    ushort* hG1 = (ushort*)ws;                  ws += NH * 2;            //  9.4 MB
    float*  cs  = (float*)ws;                   ws += NH * 4;            // 18.9 MB
    ushort* Bp  = (ushort*)ws;                                           // 336 KB

    hipMemsetAsync(cs, 0, NH * 4, stream);

    conv_x_bf16<<<(int)((NX / 4 + 255) / 256), 256, 0, stream>>>(x, xbf, (int)(NX / 4));
    prep_w<<<(4 * 21 * 256 + 255) / 256, 256, 0, stream>>>(Wx, Wh, Bp);

    float* outp = (float*)d_out;
    void* args[] = { (void*)&xbf, (void*)&hG0, (void*)&hG1, (void*)&cs,
                     (void*)&Bp,  (void*)&b,   (void*)&outp };
    hipLaunchCooperativeKernel((const void*)convlstm_persist,
                               dim3(WTOT / TW, HTOT / THH, BB), dim3(512),
                               args, 0, stream);
}